// Round 3
// baseline (152.280 us; speedup 1.0000x reference)
//
#include <hip/hip_runtime.h>
#include <hip/hip_bf16.h>

constexpr int H = 768, B = 4, L = 128, R = 48, D = 100;
constexpr int BL = B * L;          // 512
constexpr int P_SZ = BL * H;       // 393216

// d_out offsets (floats)
constexpr int OUT_FHS = 0, OUT_FHE = 512, OUT_FTS = 1024, OUT_FTE = 25600,
              OUT_BTS = 50176, OUT_BTE = 50688, OUT_BHS = 51200, OUT_BHE = 75776;

// workspace offsets (floats). P order: j=0..5 -> big_w {0,1,4,7,8,9}
constexpr int WS_BREL = 6 * P_SZ;
constexpr int WS_PRF  = WS_BREL + R * H;
constexpr int WS_PRB  = WS_PRF + R * H;
constexpr int WS_PGF  = WS_PRB + R * H;
constexpr int WS_PGB  = WS_PGF + B * H;
constexpr int WS_VF   = WS_PGB + B * H;      // (B,R,L) scores
constexpr int WS_VB   = WS_VF + B * R * L;
constexpr int WS_T2   = WS_VB + B * R * L;   // 4 x (B*L): tok . fc_w{2,3,6,7}
constexpr int WS_U    = WS_T2 + 4 * BL;      // (unused now, layout kept)
constexpr int WS_CC   = WS_U + 4 * BL;
constexpr int WS_SPAN = WS_CC + 4 * B * R;   // 16 ints
constexpr int WS_BF16 = WS_SPAN + 16;        // bf16 region (ushort base)

// ushort offsets inside bf16 region
constexpr int UB_TOK  = 0;                    // 512x768
constexpr int UB_FREL = UB_TOK + BL * H;      // 48x768
constexpr int UB_BREL = UB_FREL + R * H;      // 48x768
constexpr int UB_HGS  = UB_BREL + R * H;      // 4x768
constexpr int UB_WT   = UB_HGS + B * H;       // 10 x [n][k] 768x768 transposed bf16

typedef __attribute__((ext_vector_type(8))) short short8;
typedef __attribute__((ext_vector_type(4))) float floatx4;

__device__ __forceinline__ float tanh_fast(float x) {
    float u = __builtin_amdgcn_exp2f(x * 2.8853900817779268f);
    return 1.0f - 2.0f * __builtin_amdgcn_rcpf(1.0f + u);
}

__device__ __forceinline__ float wave_sum(float v) {
    #pragma unroll
    for (int off = 32; off; off >>= 1) v += __shfl_down(v, off);
    return v;
}

__device__ __forceinline__ ushort f2bf(float x) {
    __hip_bfloat16 h = __float2bfloat16(x);
    return __builtin_bit_cast(ushort, h);
}

__device__ __forceinline__ ushort4 f2bf4(float4 v) {
    ushort4 u;
    u.x = f2bf(v.x); u.y = f2bf(v.y); u.z = f2bf(v.z); u.w = f2bf(v.w);
    return u;
}

// ---- fused setup: boundary+t2 dots | brel(+cast) | casts | W transpose-cast
__global__ __launch_bounds__(256) void k_setup(const float* __restrict__ tok,
                                               const float* __restrict__ h_gs,
                                               const float* __restrict__ f_rel,
                                               const float* __restrict__ b_rt,
                                               const float* __restrict__ rpw,
                                               const float* __restrict__ rpb,
                                               const float* __restrict__ fcw,
                                               const float* __restrict__ fcb,
                                               const float* __restrict__ bigw,
                                               float* __restrict__ out,
                                               float* __restrict__ ws) {
    __shared__ float lds[64 * 65];
    ushort* ub = (ushort*)(ws + WS_BF16);
    int blk = blockIdx.x, tid = threadIdx.x;

    if (blk < 128) {
        // boundary heads (exact fp32 — signs drive span extraction) + t2 dots
        int wid = blk * 4 + (tid >> 6), lane = tid & 63;
        int b = wid >> 7, l = wid & 127;
        const float* tr = tok + (b * L + l) * H;
        float p0 = 0, p1 = 0, p2 = 0, p3 = 0, p4 = 0, p5 = 0, p6 = 0, p7 = 0;
        #pragma unroll
        for (int j = 0; j < H / 64; ++j) {
            int h = lane + j * 64;
            float t = tr[h];
            p0 += t * fcw[h];
            p1 += t * fcw[H + h];
            p4 += t * fcw[4 * H + h];
            p5 += t * fcw[5 * H + h];
            p2 += t * fcw[2 * H + h];
            p3 += t * fcw[3 * H + h];
            p6 += t * fcw[6 * H + h];
            p7 += t * fcw[7 * H + h];
        }
        p0 = wave_sum(p0); p1 = wave_sum(p1); p4 = wave_sum(p4); p5 = wave_sum(p5);
        p2 = wave_sum(p2); p3 = wave_sum(p3); p6 = wave_sum(p6); p7 = wave_sum(p7);
        if (lane == 0) {
            int idx = b * L + l;
            out[OUT_FHS + idx] = p0 + fcb[0];
            out[OUT_FHE + idx] = p1 + fcb[1];
            out[OUT_BTS + idx] = p4 + fcb[4];
            out[OUT_BTE + idx] = p5 + fcb[5];
            float* t2 = ws + WS_T2;
            t2[idx] = p2; t2[BL + idx] = p3; t2[2 * BL + idx] = p6; t2[3 * BL + idx] = p7;
        }
    } else if (blk < 176) {
        // b_rel_embs row -> bf16
        int r = blk - 128;
        if (tid < D) lds[tid] = b_rt[r * D + tid];
        __syncthreads();
        #pragma unroll
        for (int jj = 0; jj < 3; ++jj) {
            int h = tid + jj * 256;
            float acc = rpb[h];
            for (int k = 0; k < D; ++k) acc += lds[k] * rpw[k * H + h];
            ub[UB_BREL + r * H + h] = f2bf(acc);
        }
    } else if (blk < 200) {
        // tok -> bf16
        int base = (blk - 176) * 16384;
        #pragma unroll
        for (int i = 0; i < 16; ++i) {
            int e = base + i * 1024 + tid * 4;
            float4 v = *(const float4*)&tok[e];
            *(ushort4*)&ub[UB_TOK + e] = f2bf4(v);
        }
    } else if (blk < 204) {
        // f_rel -> bf16
        int base = (blk - 200) * 9216;
        #pragma unroll
        for (int i = 0; i < 9; ++i) {
            int e = base + i * 1024 + tid * 4;
            float4 v = *(const float4*)&f_rel[e];
            *(ushort4*)&ub[UB_FREL + e] = f2bf4(v);
        }
    } else if (blk == 204) {
        // h_gs -> bf16
        #pragma unroll
        for (int i = 0; i < 3; ++i) {
            int e = i * 1024 + tid * 4;
            float4 v = *(const float4*)&h_gs[e];
            *(ushort4*)&ub[UB_HGS + e] = f2bf4(v);
        }
    } else {
        // big_w[j] (k,n) -> WT[j] (n,k) bf16, 64x64 tiles
        int wb = blk - 205;
        int j = wb / 144, t = wb - j * 144;
        int kt = t / 12, nt = t - kt * 12;
        int k0 = kt * 64, n0 = nt * 64;
        const float* W = bigw + (size_t)j * H * H;
        ushort* WT = ub + UB_WT + (size_t)j * H * H;
        #pragma unroll
        for (int it = 0; it < 4; ++it) {
            int kk = (tid >> 4) + it * 16;
            int nn = (tid & 15) * 4;
            float4 v = *(const float4*)&W[(k0 + kk) * H + n0 + nn];
            lds[kk * 65 + nn + 0] = v.x;
            lds[kk * 65 + nn + 1] = v.y;
            lds[kk * 65 + nn + 2] = v.z;
            lds[kk * 65 + nn + 3] = v.w;
        }
        __syncthreads();
        #pragma unroll
        for (int it = 0; it < 4; ++it) {
            int nn = (tid >> 4) + it * 16;
            int kk = (tid & 15) * 4;
            float4 v;
            v.x = lds[(kk + 0) * 65 + nn];
            v.y = lds[(kk + 1) * 65 + nn];
            v.z = lds[(kk + 2) * 65 + nn];
            v.w = lds[(kk + 3) * 65 + nn];
            *(ushort4*)&WT[(n0 + nn) * H + k0 + kk] = f2bf4(v);
        }
    }
}

// ---- all 10 GEMMs, 64x64 tile, BK=64, LDS-staged bf16, 4 waves of 32x32.
// Last block = span extraction (ballot; sigmoid(x)>0.5 <=> x>0).
struct MfmaDesc { const ushort* A; const ushort* W; const float* bias; float* O; int M; };
struct MfmaArgs { MfmaDesc d[10]; int off[11]; };

constexpr int AST = 72;   // LDS row stride in shorts (36 words %32 = 4 -> 2-way free frag reads)

__global__ __launch_bounds__(256) void k_mfma(MfmaArgs args, const float* __restrict__ out,
                                              float* __restrict__ ws) {
    int blk = blockIdx.x, tid = threadIdx.x;
    int lane = tid & 63, w = tid >> 6;

    if (blk == 624) {   // span tail block: 4 waves handle 8 (ctx,b) pairs
        for (int pp = w; pp < 8; pp += 4) {
            int ctx = pp >> 2, b = pp & 3;
            const float* sp = out + (ctx ? OUT_BTS : OUT_FHS) + b * L;
            const float* ep = out + (ctx ? OUT_BTE : OUT_FHE) + b * L;
            unsigned long long s0 = __ballot(sp[lane] > 0.f);
            unsigned long long s1 = __ballot(sp[lane + 64] > 0.f);
            unsigned long long e0 = __ballot(ep[lane] > 0.f);
            unsigned long long e1 = __ballot(ep[lane + 64] > 0.f);
            if (lane == 0) {
                int s, len;
                if (s0 == 0 && s1 == 0) { s = 0; len = 0; }
                else {
                    s = s0 ? __builtin_ctzll(s0) : 64 + __builtin_ctzll(s1);
                    int e;
                    if (s < 64) {
                        unsigned long long m0 = (e0 >> s) << s;
                        e = m0 ? __builtin_ctzll(m0) : (e1 ? 64 + __builtin_ctzll(e1) : s);
                    } else {
                        int s2 = s - 64;
                        unsigned long long m1 = (e1 >> s2) << s2;
                        e = m1 ? 64 + __builtin_ctzll(m1) : s;
                    }
                    len = e - s + 1;
                }
                int* span = (int*)(ws + WS_SPAN);
                span[ctx * 8 + b] = s;
                span[ctx * 8 + 4 + b] = len;
            }
        }
        return;
    }

    int p = 0;
    while (p < 9 && blk >= args.off[p + 1]) ++p;
    MfmaDesc dd = args.d[p];
    int t = blk - args.off[p];
    int mt = t / 12, nt = t - mt * 12;
    int m0 = mt * 64, n0 = nt * 64;

    __shared__ __align__(16) ushort As[64 * AST];
    __shared__ __align__(16) ushort Bs[64 * AST];

    int seg = tid & 7;            // 8 x 16B segments per 64-bf16 row
    int row2 = tid >> 3;          // 0..31, +32 on second pass
    int Mm1 = dd.M - 1;

    int wm = w >> 1, wn = w & 1;
    int lr = lane & 15, q = lane >> 4;
    floatx4 acc[2][2] = {};

    for (int k0 = 0; k0 < H; k0 += 64) {
        // stage A (rows clamped to M-1) and B, coalesced short8 loads
        #pragma unroll
        for (int it = 0; it < 2; ++it) {
            int r = row2 + it * 32;
            int ar = min(m0 + r, Mm1);
            *(short8*)&As[r * AST + seg * 8] = *(const short8*)&dd.A[ar * H + k0 + seg * 8];
            *(short8*)&Bs[r * AST + seg * 8] = *(const short8*)&dd.W[(n0 + r) * H + k0 + seg * 8];
        }
        __syncthreads();
        #pragma unroll
        for (int ks = 0; ks < 64; ks += 32) {
            short8 a0 = *(const short8*)&As[(wm * 32 + lr) * AST + ks + q * 8];
            short8 a1 = *(const short8*)&As[(wm * 32 + 16 + lr) * AST + ks + q * 8];
            short8 b0 = *(const short8*)&Bs[(wn * 32 + lr) * AST + ks + q * 8];
            short8 b1 = *(const short8*)&Bs[(wn * 32 + 16 + lr) * AST + ks + q * 8];
            acc[0][0] = __builtin_amdgcn_mfma_f32_16x16x32_bf16(a0, b0, acc[0][0], 0, 0, 0);
            acc[0][1] = __builtin_amdgcn_mfma_f32_16x16x32_bf16(a0, b1, acc[0][1], 0, 0, 0);
            acc[1][0] = __builtin_amdgcn_mfma_f32_16x16x32_bf16(a1, b0, acc[1][0], 0, 0, 0);
            acc[1][1] = __builtin_amdgcn_mfma_f32_16x16x32_bf16(a1, b1, acc[1][1], 0, 0, 0);
        }
        __syncthreads();
    }

    #pragma unroll
    for (int j = 0; j < 2; ++j) {
        int col = n0 + wn * 32 + j * 16 + lr;
        float bv = dd.bias[col];
        #pragma unroll
        for (int i = 0; i < 2; ++i) {
            int rowb = m0 + wm * 32 + i * 16 + q * 4;
            #pragma unroll
            for (int rr = 0; rr < 4; ++rr) {
                int row = rowb + rr;
                if (row < dd.M) dd.O[row * H + col] = acc[i][j][rr] + bv;
            }
        }
    }
}

// ---- attention scores: v[b,r,l] = sum_h tanh(px+pg+pr)*vw + vb, 4 l's per block
__global__ __launch_bounds__(256) void k_attn_v(float* __restrict__ ws,
                                                const float* __restrict__ fcw,
                                                const float* __restrict__ fcb) {
    int ctx = blockIdx.y;
    int b = blockIdx.x >> 5;
    int l0 = (blockIdx.x & 31) * 4;
    int lane = threadIdx.x & 63, w = threadIdx.x >> 6;

    const float* pxb = ws + (ctx ? 3 : 2) * P_SZ + (b * L + l0) * H;
    const float* pg = ws + (ctx ? WS_PGB : WS_PGF) + b * H;
    const float* pr = ws + (ctx ? WS_PRB : WS_PRF);
    float* vout = ws + (ctx ? WS_VB : WS_VF) + b * R * L + l0;

    float x[4][12], vw[12];
    #pragma unroll
    for (int j = 0; j < 12; ++j) {
        int h = lane + j * 64;
        float g = pg[h];
        vw[j] = fcw[8 * H + h];
        #pragma unroll
        for (int ll = 0; ll < 4; ++ll) x[ll][j] = pxb[ll * H + h] + g;
    }
    float vb = fcb[8];

    for (int r = w; r < R; r += 4) {
        const float* prr = pr + r * H;
        float pv[12];
        #pragma unroll
        for (int j = 0; j < 12; ++j) pv[j] = prr[lane + j * 64];
        float p[4] = {0.f, 0.f, 0.f, 0.f};
        #pragma unroll
        for (int j = 0; j < 12; ++j) {
            float pvj = pv[j], vwj = vw[j];
            #pragma unroll
            for (int ll = 0; ll < 4; ++ll)
                p[ll] += tanh_fast(x[ll][j] + pvj) * vwj;
        }
        #pragma unroll
        for (int ll = 0; ll < 4; ++ll) p[ll] = wave_sum(p[ll]);
        if (lane == 0) {
            #pragma unroll
            for (int ll = 0; ll < 4; ++ll) vout[r * L + ll] = p[ll] + vb;
        }
    }
}

// ---- fused epilogue: softmax+c (recomputed per block), u-dots, broadcast write
__global__ __launch_bounds__(256) void k_epi(const float* __restrict__ tok,
                                             const float* __restrict__ fcw,
                                             const float* __restrict__ fcb,
                                             float* __restrict__ ws,
                                             float* __restrict__ out) {
    int ctx = blockIdx.z, b = blockIdx.y, l0 = blockIdx.x * 32;
    int lane = threadIdx.x & 63, w = threadIdx.x >> 6;
    __shared__ float c2[2][R];
    __shared__ float uu[2][32];

    // phase A: softmax over L + c[b,r] for both heads of this ctx
    const float* vbase = ws + (ctx ? WS_VB : WS_VF) + b * R * L;
    const float* tA = ws + WS_T2 + (ctx * 2 + 0) * BL + b * L;
    const float* tB = ws + WS_T2 + (ctx * 2 + 1) * BL + b * L;
    for (int r = w; r < R; r += 4) {
        const float* vr = vbase + r * L;
        float x0 = vr[lane], x1 = vr[lane + 64];
        float m = fmaxf(x0, x1);
        #pragma unroll
        for (int off = 32; off; off >>= 1) m = fmaxf(m, __shfl_xor(m, off));
        constexpr float LOG2E = 1.4426950408889634f;
        float e0 = __builtin_amdgcn_exp2f((x0 - m) * LOG2E);
        float e1 = __builtin_amdgcn_exp2f((x1 - m) * LOG2E);
        float s = e0 + e1;
        float pa = e0 * tA[lane] + e1 * tA[lane + 64];
        float pb = e0 * tB[lane] + e1 * tB[lane + 64];
        #pragma unroll
        for (int off = 32; off; off >>= 1) {
            s += __shfl_xor(s, off);
            pa += __shfl_xor(pa, off);
            pb += __shfl_xor(pb, off);
        }
        if (lane == 0) {
            float inv = __builtin_amdgcn_rcpf(s);
            c2[0][r] = pa * inv;
            c2[1][r] = pb * inv;
        }
    }

    // phase B: u[l] for 32 l's (8 per wave)
    const int* span = (const int*)(ws + WS_SPAN);
    int s0 = span[ctx * 8 + b], sl = span[ctx * 8 + 4 + b];
    const float* wA = fcw + (ctx ? 6 : 2) * H;
    const float* wB = fcw + (ctx ? 7 : 3) * H;
    const float* pX = ws + (ctx ? 5 : 4) * (size_t)P_SZ;   // tok@W8 / tok@W9 (+bias)
    const float* pG = ws + (ctx ? 1 : 0) * (size_t)P_SZ;   // gathered-span proj (+bias)
    #pragma unroll
    for (int i = 0; i < 8; ++i) {
        int l_loc = w * 8 + i, l = l0 + l_loc;
        bool msk = l < sl;
        float mf = msk ? 1.f : 0.f;
        const float* tr = tok + (b * L + l) * H;
        const float* xr = pX + (b * L + l) * H;
        const float* gr = pG + (b * L + (msk ? s0 + l : 0)) * H;
        float pf = 0.f, pg2 = 0.f;
        #pragma unroll
        for (int j = 0; j < 12; ++j) {
            int h = lane + j * 64;
            float sv = tr[h] + xr[h] + mf * gr[h];
            pf += sv * wA[h];
            pg2 += sv * wB[h];
        }
        pf = wave_sum(pf); pg2 = wave_sum(pg2);
        if (lane == 0) { uu[0][l_loc] = pf; uu[1][l_loc] = pg2; }
    }
    __syncthreads();

    // phase C: out[b,l,r] = u[l] + c[r] + bias
    const int out_off4[4] = {OUT_FTS, OUT_FTE, OUT_BHS, OUT_BHE};
    float bias0 = fcb[ctx ? 6 : 2], bias1 = fcb[ctx ? 7 : 3];
    int o0 = out_off4[ctx * 2 + 0], o1 = out_off4[ctx * 2 + 1];
    for (int idx = threadIdx.x; idx < 32 * R; idx += 256) {
        int l_loc = idx / R, r = idx - l_loc * R;
        int o = b * (L * R) + (l0 + l_loc) * R + r;
        out[o0 + o] = uu[0][l_loc] + c2[0][r] + bias0;
        out[o1 + o] = uu[1][l_loc] + c2[1][r] + bias1;
    }
}

extern "C" void kernel_launch(void* const* d_in, const int* in_sizes, int n_in,
                              void* d_out, int out_size, void* d_ws, size_t ws_size,
                              hipStream_t stream) {
    const float* h_gs  = (const float*)d_in[0];
    const float* tok   = (const float*)d_in[1];
    const float* f_rel = (const float*)d_in[2];
    const float* b_rt  = (const float*)d_in[3];
    const float* rpw   = (const float*)d_in[4];
    const float* rpb   = (const float*)d_in[5];
    const float* fcw   = (const float*)d_in[6];
    const float* fcb   = (const float*)d_in[7];
    const float* bigw  = (const float*)d_in[8];
    const float* bigb  = (const float*)d_in[9];
    float* out = (float*)d_out;
    float* ws  = (float*)d_ws;
    const ushort* ub = (const ushort*)(ws + WS_BF16);

    k_setup<<<1645, 256, 0, stream>>>(tok, h_gs, f_rel, b_rt, rpw, rpb, fcw, fcb, bigw, out, ws);

    MfmaArgs ma;
    const int wj[6] = {0, 1, 4, 7, 8, 9};
    for (int j = 0; j < 6; ++j)
        ma.d[j] = MfmaDesc{ub + UB_TOK, ub + UB_WT + (size_t)wj[j] * H * H,
                           bigb + wj[j] * H, ws + (size_t)j * P_SZ, BL};
    ma.d[6] = MfmaDesc{ub + UB_FREL, ub + UB_WT + 2 * (size_t)H * H, bigb + 2 * H, ws + WS_PRF, R};
    ma.d[7] = MfmaDesc{ub + UB_BREL, ub + UB_WT + 5 * (size_t)H * H, bigb + 5 * H, ws + WS_PRB, R};
    ma.d[8] = MfmaDesc{ub + UB_HGS,  ub + UB_WT + 3 * (size_t)H * H, bigb + 3 * H, ws + WS_PGF, B};
    ma.d[9] = MfmaDesc{ub + UB_HGS,  ub + UB_WT + 6 * (size_t)H * H, bigb + 6 * H, ws + WS_PGB, B};
    int off = 0;
    for (int p = 0; p < 10; ++p) {
        ma.off[p] = off;
        int mtiles = (ma.d[p].M + 63) / 64;
        off += mtiles * 12;
    }
    ma.off[10] = off;   // 624
    k_mfma<<<off + 1, 256, 0, stream>>>(ma, out, ws);   // +1 span tail block

    k_attn_v<<<dim3(128, 2), 256, 0, stream>>>(ws, fcw, fcb);
    k_epi<<<dim3(4, 4, 2), 256, 0, stream>>>(tok, fcw, fcb, ws, out);
}

// Round 5
// 147.681 us; speedup vs baseline: 1.0311x; 1.0311x over previous
//
#include <hip/hip_runtime.h>
#include <hip/hip_bf16.h>

constexpr int H = 768, B = 4, L = 128, R = 48, D = 100;
constexpr int BL = B * L;          // 512
constexpr int P_SZ = BL * H;       // 393216

// d_out offsets (floats)
constexpr int OUT_FHS = 0, OUT_FHE = 512, OUT_FTS = 1024, OUT_FTE = 25600,
              OUT_BTS = 50176, OUT_BTE = 50688, OUT_BHS = 51200, OUT_BHE = 75776;

// workspace offsets (floats). P order: j=0..5 -> big_w {0,1,4,7,8,9}
constexpr int WS_BREL = 6 * P_SZ;
constexpr int WS_PRF  = WS_BREL + R * H;
constexpr int WS_PRB  = WS_PRF + R * H;
constexpr int WS_PGF  = WS_PRB + R * H;
constexpr int WS_PGB  = WS_PGF + B * H;
constexpr int WS_VF   = WS_PGB + B * H;      // (B,R,L) scores
constexpr int WS_VB   = WS_VF + B * R * L;
constexpr int WS_T2   = WS_VB + B * R * L;   // 4 x (B*L): tok . fc_w{2,3,6,7}
constexpr int WS_U    = WS_T2 + 4 * BL;
constexpr int WS_CC   = WS_U + 4 * BL;
constexpr int WS_SPAN = WS_CC + 4 * B * R;   // 16 ints
constexpr int WS_BF16 = WS_SPAN + 16;        // bf16 region (ushort base)

// ushort offsets inside bf16 region
constexpr int UB_TOK  = 0;                    // 512x768
constexpr int UB_FREL = UB_TOK + BL * H;      // 48x768
constexpr int UB_BREL = UB_FREL + R * H;      // 48x768
constexpr int UB_HGS  = UB_BREL + R * H;      // 4x768
constexpr int UB_WT   = UB_HGS + B * H;       // 10 x [n][k] 768x768 transposed bf16

typedef __attribute__((ext_vector_type(8))) short short8;
typedef __attribute__((ext_vector_type(4))) float floatx4;

__device__ __forceinline__ float wave_sum(float v) {
    #pragma unroll
    for (int off = 32; off; off >>= 1) v += __shfl_down(v, off);
    return v;
}

__device__ __forceinline__ ushort f2bf(float x) {
    __hip_bfloat16 h = __float2bfloat16(x);
    return __builtin_bit_cast(ushort, h);
}

__device__ __forceinline__ ushort4 f2bf4(float4 v) {
    ushort4 u;
    u.x = f2bf(v.x); u.y = f2bf(v.y); u.z = f2bf(v.z); u.w = f2bf(v.w);
    return u;
}

// ---- fused setup: boundary+t2 dots | brel(+cast) | casts | W transpose-cast
__global__ __launch_bounds__(256) void k_setup(const float* __restrict__ tok,
                                               const float* __restrict__ h_gs,
                                               const float* __restrict__ f_rel,
                                               const float* __restrict__ b_rt,
                                               const float* __restrict__ rpw,
                                               const float* __restrict__ rpb,
                                               const float* __restrict__ fcw,
                                               const float* __restrict__ fcb,
                                               const float* __restrict__ bigw,
                                               float* __restrict__ out,
                                               float* __restrict__ ws) {
    __shared__ float lds[64 * 65];
    ushort* ub = (ushort*)(ws + WS_BF16);
    int blk = blockIdx.x, tid = threadIdx.x;

    if (blk < 128) {
        // boundary heads (exact fp32 — signs drive span extraction) + t2 dots
        int wid = blk * 4 + (tid >> 6), lane = tid & 63;
        int b = wid >> 7, l = wid & 127;
        const float* tr = tok + (b * L + l) * H;
        float p0 = 0, p1 = 0, p2 = 0, p3 = 0, p4 = 0, p5 = 0, p6 = 0, p7 = 0;
        #pragma unroll
        for (int j = 0; j < H / 64; ++j) {
            int h = lane + j * 64;
            float t = tr[h];
            p0 += t * fcw[h];
            p1 += t * fcw[H + h];
            p4 += t * fcw[4 * H + h];
            p5 += t * fcw[5 * H + h];
            p2 += t * fcw[2 * H + h];
            p3 += t * fcw[3 * H + h];
            p6 += t * fcw[6 * H + h];
            p7 += t * fcw[7 * H + h];
        }
        p0 = wave_sum(p0); p1 = wave_sum(p1); p4 = wave_sum(p4); p5 = wave_sum(p5);
        p2 = wave_sum(p2); p3 = wave_sum(p3); p6 = wave_sum(p6); p7 = wave_sum(p7);
        if (lane == 0) {
            int idx = b * L + l;
            out[OUT_FHS + idx] = p0 + fcb[0];
            out[OUT_FHE + idx] = p1 + fcb[1];
            out[OUT_BTS + idx] = p4 + fcb[4];
            out[OUT_BTE + idx] = p5 + fcb[5];
            float* t2 = ws + WS_T2;
            t2[idx] = p2; t2[BL + idx] = p3; t2[2 * BL + idx] = p6; t2[3 * BL + idx] = p7;
        }
    } else if (blk < 176) {
        // b_rel_embs row -> bf16
        int r = blk - 128;
        if (tid < D) lds[tid] = b_rt[r * D + tid];
        __syncthreads();
        #pragma unroll
        for (int jj = 0; jj < 3; ++jj) {
            int h = tid + jj * 256;
            float acc = rpb[h];
            for (int k = 0; k < D; ++k) acc += lds[k] * rpw[k * H + h];
            ub[UB_BREL + r * H + h] = f2bf(acc);
        }
    } else if (blk < 200) {
        // tok -> bf16
        int base = (blk - 176) * 16384;
        #pragma unroll
        for (int i = 0; i < 16; ++i) {
            int e = base + i * 1024 + tid * 4;
            float4 v = *(const float4*)&tok[e];
            *(ushort4*)&ub[UB_TOK + e] = f2bf4(v);
        }
    } else if (blk < 204) {
        // f_rel -> bf16
        int base = (blk - 200) * 9216;
        #pragma unroll
        for (int i = 0; i < 9; ++i) {
            int e = base + i * 1024 + tid * 4;
            float4 v = *(const float4*)&f_rel[e];
            *(ushort4*)&ub[UB_FREL + e] = f2bf4(v);
        }
    } else if (blk == 204) {
        // h_gs -> bf16
        #pragma unroll
        for (int i = 0; i < 3; ++i) {
            int e = i * 1024 + tid * 4;
            float4 v = *(const float4*)&h_gs[e];
            *(ushort4*)&ub[UB_HGS + e] = f2bf4(v);
        }
    } else {
        // big_w[j] (k,n) -> WT[j] (n,k) bf16, 64x64 tiles
        int wb = blk - 205;
        int j = wb / 144, t = wb - j * 144;
        int kt = t / 12, nt = t - kt * 12;
        int k0 = kt * 64, n0 = nt * 64;
        const float* W = bigw + (size_t)j * H * H;
        ushort* WT = ub + UB_WT + (size_t)j * H * H;
        #pragma unroll
        for (int it = 0; it < 4; ++it) {
            int kk = (tid >> 4) + it * 16;
            int nn = (tid & 15) * 4;
            float4 v = *(const float4*)&W[(k0 + kk) * H + n0 + nn];
            lds[kk * 65 + nn + 0] = v.x;
            lds[kk * 65 + nn + 1] = v.y;
            lds[kk * 65 + nn + 2] = v.z;
            lds[kk * 65 + nn + 3] = v.w;
        }
        __syncthreads();
        #pragma unroll
        for (int it = 0; it < 4; ++it) {
            int nn = (tid >> 4) + it * 16;
            int kk = (tid & 15) * 4;
            float4 v;
            v.x = lds[(kk + 0) * 65 + nn];
            v.y = lds[(kk + 1) * 65 + nn];
            v.z = lds[(kk + 2) * 65 + nn];
            v.w = lds[(kk + 3) * 65 + nn];
            *(ushort4*)&WT[(n0 + nn) * H + k0 + kk] = f2bf4(v);
        }
    }
}

// ---- all 10 GEMMs, 64x64 tile, BK=64, LDS-staged bf16, 4 waves of 32x32.
// Last block = span extraction (ballot; sigmoid(x)>0.5 <=> x>0).
struct MfmaDesc { const ushort* A; const ushort* W; const float* bias; float* O; int M; };
struct MfmaArgs { MfmaDesc d[10]; int off[11]; };

constexpr int AST = 72;   // LDS row stride in shorts

__global__ __launch_bounds__(256) void k_mfma(MfmaArgs args, const float* __restrict__ out,
                                              float* __restrict__ ws) {
    int blk = blockIdx.x, tid = threadIdx.x;
    int lane = tid & 63, w = tid >> 6;

    if (blk == 624) {   // span tail block
        for (int pp = w; pp < 8; pp += 4) {
            int ctx = pp >> 2, b = pp & 3;
            const float* sp = out + (ctx ? OUT_BTS : OUT_FHS) + b * L;
            const float* ep = out + (ctx ? OUT_BTE : OUT_FHE) + b * L;
            unsigned long long s0 = __ballot(sp[lane] > 0.f);
            unsigned long long s1 = __ballot(sp[lane + 64] > 0.f);
            unsigned long long e0 = __ballot(ep[lane] > 0.f);
            unsigned long long e1 = __ballot(ep[lane + 64] > 0.f);
            if (lane == 0) {
                int s, len;
                if (s0 == 0 && s1 == 0) { s = 0; len = 0; }
                else {
                    s = s0 ? __builtin_ctzll(s0) : 64 + __builtin_ctzll(s1);
                    int e;
                    if (s < 64) {
                        unsigned long long m0 = (e0 >> s) << s;
                        e = m0 ? __builtin_ctzll(m0) : (e1 ? 64 + __builtin_ctzll(e1) : s);
                    } else {
                        int s2 = s - 64;
                        unsigned long long m1 = (e1 >> s2) << s2;
                        e = m1 ? 64 + __builtin_ctzll(m1) : s;
                    }
                    len = e - s + 1;
                }
                int* span = (int*)(ws + WS_SPAN);
                span[ctx * 8 + b] = s;
                span[ctx * 8 + 4 + b] = len;
            }
        }
        return;
    }

    int p = 0;
    while (p < 9 && blk >= args.off[p + 1]) ++p;
    MfmaDesc dd = args.d[p];
    int t = blk - args.off[p];
    int mt = t / 12, nt = t - mt * 12;
    int m0 = mt * 64, n0 = nt * 64;

    __shared__ __align__(16) ushort As[64 * AST];
    __shared__ __align__(16) ushort Bs[64 * AST];

    int seg = tid & 7;
    int row2 = tid >> 3;
    int Mm1 = dd.M - 1;

    int wm = w >> 1, wn = w & 1;
    int lr = lane & 15, q = lane >> 4;
    floatx4 acc[2][2] = {};

    for (int k0 = 0; k0 < H; k0 += 64) {
        #pragma unroll
        for (int it = 0; it < 2; ++it) {
            int r = row2 + it * 32;
            int ar = min(m0 + r, Mm1);
            *(short8*)&As[r * AST + seg * 8] = *(const short8*)&dd.A[ar * H + k0 + seg * 8];
            *(short8*)&Bs[r * AST + seg * 8] = *(const short8*)&dd.W[(n0 + r) * H + k0 + seg * 8];
        }
        __syncthreads();
        #pragma unroll
        for (int ks = 0; ks < 64; ks += 32) {
            short8 a0 = *(const short8*)&As[(wm * 32 + lr) * AST + ks + q * 8];
            short8 a1 = *(const short8*)&As[(wm * 32 + 16 + lr) * AST + ks + q * 8];
            short8 b0 = *(const short8*)&Bs[(wn * 32 + lr) * AST + ks + q * 8];
            short8 b1 = *(const short8*)&Bs[(wn * 32 + 16 + lr) * AST + ks + q * 8];
            acc[0][0] = __builtin_amdgcn_mfma_f32_16x16x32_bf16(a0, b0, acc[0][0], 0, 0, 0);
            acc[0][1] = __builtin_amdgcn_mfma_f32_16x16x32_bf16(a0, b1, acc[0][1], 0, 0, 0);
            acc[1][0] = __builtin_amdgcn_mfma_f32_16x16x32_bf16(a1, b0, acc[1][0], 0, 0, 0);
            acc[1][1] = __builtin_amdgcn_mfma_f32_16x16x32_bf16(a1, b1, acc[1][1], 0, 0, 0);
        }
        __syncthreads();
    }

    #pragma unroll
    for (int j = 0; j < 2; ++j) {
        int col = n0 + wn * 32 + j * 16 + lr;
        float bv = dd.bias[col];
        #pragma unroll
        for (int i = 0; i < 2; ++i) {
            int rowb = m0 + wm * 32 + i * 16 + q * 4;
            #pragma unroll
            for (int rr = 0; rr < 4; ++rr) {
                int row = rowb + rr;
                if (row < dd.M) dd.O[row * H + col] = acc[i][j][rr] + bv;
            }
        }
    }
}

// ---- attention scores: v[b,r,l] = sum_h tanh(x+pr)*vw + vb, 4 l's per block.
// Round-3 proven grid/indexing; arithmetic-only change inside:
// tanh(x+p) = 1 - 2/(1 + e^{2x}*e^{2p}), e^{2x} hoisted per-l, e^{2p} per-r.
__global__ __launch_bounds__(256) void k_attn_v(float* __restrict__ ws,
                                                const float* __restrict__ fcw,
                                                const float* __restrict__ fcb) {
    int ctx = blockIdx.y;
    int b = blockIdx.x >> 5;
    int l0 = (blockIdx.x & 31) * 4;
    int lane = threadIdx.x & 63, w = threadIdx.x >> 6;
    constexpr float TWO_LOG2E = 2.8853900817779268f;

    const float* pxb = ws + (ctx ? 3 : 2) * P_SZ + (b * L + l0) * H;
    const float* pg = ws + (ctx ? WS_PGB : WS_PGF) + b * H;
    const float* pr = ws + (ctx ? WS_PRB : WS_PRF);
    float* vout = ws + (ctx ? WS_VB : WS_VF) + b * R * L + l0;

    float ex[4][12], vw[12];
    float svw = 0.f;
    #pragma unroll
    for (int j = 0; j < 12; ++j) {
        int h = lane + j * 64;
        float g = pg[h];
        vw[j] = fcw[8 * H + h];
        svw += vw[j];
        #pragma unroll
        for (int ll = 0; ll < 4; ++ll)
            ex[ll][j] = __builtin_amdgcn_exp2f((pxb[ll * H + h] + g) * TWO_LOG2E);
    }
    float vb = fcb[8];

    for (int r = w; r < R; r += 4) {
        const float* prr = pr + r * H;
        float ep[12];
        #pragma unroll
        for (int j = 0; j < 12; ++j)
            ep[j] = __builtin_amdgcn_exp2f(prr[lane + j * 64] * TWO_LOG2E);
        float n[4] = {0.f, 0.f, 0.f, 0.f};
        #pragma unroll
        for (int j = 0; j < 12; ++j) {
            float vwj = vw[j], epj = ep[j];
            #pragma unroll
            for (int ll = 0; ll < 4; ++ll)
                n[ll] += vwj * __builtin_amdgcn_rcpf(1.0f + ex[ll][j] * epj);
        }
        float p[4];
        #pragma unroll
        for (int ll = 0; ll < 4; ++ll) p[ll] = wave_sum(svw - 2.f * n[ll]);
        if (lane == 0) {
            #pragma unroll
            for (int ll = 0; ll < 4; ++ll) vout[r * L + ll] = p[ll] + vb;
        }
    }
}

// ---- fused epilogue: softmax+c (recomputed per block), u-dots, broadcast write
// (round-3 proven version, unchanged)
__global__ __launch_bounds__(256) void k_epi(const float* __restrict__ tok,
                                             const float* __restrict__ fcw,
                                             const float* __restrict__ fcb,
                                             float* __restrict__ ws,
                                             float* __restrict__ out) {
    int ctx = blockIdx.z, b = blockIdx.y, l0 = blockIdx.x * 32;
    int lane = threadIdx.x & 63, w = threadIdx.x >> 6;
    __shared__ float c2[2][R];
    __shared__ float uu[2][32];

    // phase A: softmax over L + c[b,r] for both heads of this ctx
    const float* vbase = ws + (ctx ? WS_VB : WS_VF) + b * R * L;
    const float* tA = ws + WS_T2 + (ctx * 2 + 0) * BL + b * L;
    const float* tB = ws + WS_T2 + (ctx * 2 + 1) * BL + b * L;
    for (int r = w; r < R; r += 4) {
        const float* vr = vbase + r * L;
        float x0 = vr[lane], x1 = vr[lane + 64];
        float m = fmaxf(x0, x1);
        #pragma unroll
        for (int off = 32; off; off >>= 1) m = fmaxf(m, __shfl_xor(m, off));
        constexpr float LOG2E = 1.4426950408889634f;
        float e0 = __builtin_amdgcn_exp2f((x0 - m) * LOG2E);
        float e1 = __builtin_amdgcn_exp2f((x1 - m) * LOG2E);
        float s = e0 + e1;
        float pa = e0 * tA[lane] + e1 * tA[lane + 64];
        float pb = e0 * tB[lane] + e1 * tB[lane + 64];
        #pragma unroll
        for (int off = 32; off; off >>= 1) {
            s += __shfl_xor(s, off);
            pa += __shfl_xor(pa, off);
            pb += __shfl_xor(pb, off);
        }
        if (lane == 0) {
            float inv = __builtin_amdgcn_rcpf(s);
            c2[0][r] = pa * inv;
            c2[1][r] = pb * inv;
        }
    }

    // phase B: u[l] for 32 l's (8 per wave)
    const int* span = (const int*)(ws + WS_SPAN);
    int s0 = span[ctx * 8 + b], sl = span[ctx * 8 + 4 + b];
    const float* wA = fcw + (ctx ? 6 : 2) * H;
    const float* wB = fcw + (ctx ? 7 : 3) * H;
    const float* pX = ws + (ctx ? 5 : 4) * (size_t)P_SZ;
    const float* pG = ws + (ctx ? 1 : 0) * (size_t)P_SZ;
    #pragma unroll
    for (int i = 0; i < 8; ++i) {
        int l_loc = w * 8 + i, l = l0 + l_loc;
        bool msk = l < sl;
        float mf = msk ? 1.f : 0.f;
        const float* tr = tok + (b * L + l) * H;
        const float* xr = pX + (b * L + l) * H;
        const float* gr = pG + (b * L + (msk ? s0 + l : 0)) * H;
        float pf = 0.f, pg2 = 0.f;
        #pragma unroll
        for (int j = 0; j < 12; ++j) {
            int h = lane + j * 64;
            float sv = tr[h] + xr[h] + mf * gr[h];
            pf += sv * wA[h];
            pg2 += sv * wB[h];
        }
        pf = wave_sum(pf); pg2 = wave_sum(pg2);
        if (lane == 0) { uu[0][l_loc] = pf; uu[1][l_loc] = pg2; }
    }
    __syncthreads();

    // phase C: out[b,l,r] = u[l] + c[r] + bias
    const int out_off4[4] = {OUT_FTS, OUT_FTE, OUT_BHS, OUT_BHE};
    float bias0 = fcb[ctx ? 6 : 2], bias1 = fcb[ctx ? 7 : 3];
    int o0 = out_off4[ctx * 2 + 0], o1 = out_off4[ctx * 2 + 1];
    for (int idx = threadIdx.x; idx < 32 * R; idx += 256) {
        int l_loc = idx / R, r = idx - l_loc * R;
        int o = b * (L * R) + (l0 + l_loc) * R + r;
        out[o0 + o] = uu[0][l_loc] + c2[0][r] + bias0;
        out[o1 + o] = uu[1][l_loc] + c2[1][r] + bias1;
    }
}

extern "C" void kernel_launch(void* const* d_in, const int* in_sizes, int n_in,
                              void* d_out, int out_size, void* d_ws, size_t ws_size,
                              hipStream_t stream) {
    const float* h_gs  = (const float*)d_in[0];
    const float* tok   = (const float*)d_in[1];
    const float* f_rel = (const float*)d_in[2];
    const float* b_rt  = (const float*)d_in[3];
    const float* rpw   = (const float*)d_in[4];
    const float* rpb   = (const float*)d_in[5];
    const float* fcw   = (const float*)d_in[6];
    const float* fcb   = (const float*)d_in[7];
    const float* bigw  = (const float*)d_in[8];
    const float* bigb  = (const float*)d_in[9];
    float* out = (float*)d_out;
    float* ws  = (float*)d_ws;
    const ushort* ub = (const ushort*)(ws + WS_BF16);

    k_setup<<<1645, 256, 0, stream>>>(tok, h_gs, f_rel, b_rt, rpw, rpb, fcw, fcb, bigw, out, ws);

    MfmaArgs ma;
    const int wj[6] = {0, 1, 4, 7, 8, 9};
    for (int j = 0; j < 6; ++j)
        ma.d[j] = MfmaDesc{ub + UB_TOK, ub + UB_WT + (size_t)wj[j] * H * H,
                           bigb + wj[j] * H, ws + (size_t)j * P_SZ, BL};
    ma.d[6] = MfmaDesc{ub + UB_FREL, ub + UB_WT + 2 * (size_t)H * H, bigb + 2 * H, ws + WS_PRF, R};
    ma.d[7] = MfmaDesc{ub + UB_BREL, ub + UB_WT + 5 * (size_t)H * H, bigb + 5 * H, ws + WS_PRB, R};
    ma.d[8] = MfmaDesc{ub + UB_HGS,  ub + UB_WT + 3 * (size_t)H * H, bigb + 3 * H, ws + WS_PGF, B};
    ma.d[9] = MfmaDesc{ub + UB_HGS,  ub + UB_WT + 6 * (size_t)H * H, bigb + 6 * H, ws + WS_PGB, B};
    int off = 0;
    for (int p = 0; p < 10; ++p) {
        ma.off[p] = off;
        int mtiles = (ma.d[p].M + 63) / 64;
        off += mtiles * 12;
    }
    ma.off[10] = off;   // 624
    k_mfma<<<off + 1, 256, 0, stream>>>(ma, out, ws);

    k_attn_v<<<dim3(128, 2), 256, 0, stream>>>(ws, fcw, fcb);
    k_epi<<<dim3(4, 4, 2), 256, 0, stream>>>(tok, fcw, fcb, ws, out);
}

// Round 6
// 142.680 us; speedup vs baseline: 1.0673x; 1.0350x over previous
//
#include <hip/hip_runtime.h>
#include <hip/hip_bf16.h>

constexpr int H = 768, B = 4, L = 128, R = 48, D = 100;
constexpr int BL = B * L;          // 512
constexpr int P_SZ = BL * H;       // 393216

// d_out offsets (floats)
constexpr int OUT_FHS = 0, OUT_FHE = 512, OUT_FTS = 1024, OUT_FTE = 25600,
              OUT_BTS = 50176, OUT_BTE = 50688, OUT_BHS = 51200, OUT_BHE = 75776;

// workspace offsets (floats). P order: j=0..5 -> big_w {0,1,4,7,8,9}
constexpr int WS_BREL = 6 * P_SZ;
constexpr int WS_PRF  = WS_BREL + R * H;
constexpr int WS_PRB  = WS_PRF + R * H;
constexpr int WS_PGF  = WS_PRB + R * H;
constexpr int WS_PGB  = WS_PGF + B * H;
constexpr int WS_VF   = WS_PGB + B * H;      // (B,R,L) scores
constexpr int WS_VB   = WS_VF + B * R * L;
constexpr int WS_T2   = WS_VB + B * R * L;   // 4 x (B*L): tok . fc_w{2,3,6,7}
constexpr int WS_U    = WS_T2 + 4 * BL;
constexpr int WS_CC   = WS_U + 4 * BL;
constexpr int WS_SPAN = WS_CC + 4 * B * R;   // 16 ints
constexpr int WS_BF16 = WS_SPAN + 16;        // bf16 region (ushort base)

// ushort offsets inside bf16 region
constexpr int UB_TOK  = 0;                    // 512x768
constexpr int UB_FREL = UB_TOK + BL * H;      // 48x768
constexpr int UB_BREL = UB_FREL + R * H;      // 48x768
constexpr int UB_HGS  = UB_BREL + R * H;      // 4x768
constexpr int UB_WT   = UB_HGS + B * H;       // 10 x [n][k] 768x768 transposed bf16

typedef __attribute__((ext_vector_type(8))) short short8;
typedef __attribute__((ext_vector_type(4))) float floatx4;

__device__ __forceinline__ float wave_sum(float v) {
    #pragma unroll
    for (int off = 32; off; off >>= 1) v += __shfl_down(v, off);
    return v;
}

__device__ __forceinline__ ushort f2bf(float x) {
    __hip_bfloat16 h = __float2bfloat16(x);
    return __builtin_bit_cast(ushort, h);
}

__device__ __forceinline__ ushort4 f2bf4(float4 v) {
    ushort4 u;
    u.x = f2bf(v.x); u.y = f2bf(v.y); u.z = f2bf(v.z); u.w = f2bf(v.w);
    return u;
}

// ---- fused setup: boundary+t2 dots | brel(+cast) | casts | W transpose-cast
__global__ __launch_bounds__(256) void k_setup(const float* __restrict__ tok,
                                               const float* __restrict__ h_gs,
                                               const float* __restrict__ f_rel,
                                               const float* __restrict__ b_rt,
                                               const float* __restrict__ rpw,
                                               const float* __restrict__ rpb,
                                               const float* __restrict__ fcw,
                                               const float* __restrict__ fcb,
                                               const float* __restrict__ bigw,
                                               float* __restrict__ out,
                                               float* __restrict__ ws) {
    __shared__ float lds[64 * 65];
    ushort* ub = (ushort*)(ws + WS_BF16);
    int blk = blockIdx.x, tid = threadIdx.x;

    if (blk < 128) {
        // boundary heads (exact fp32 — signs drive span extraction) + t2 dots
        int wid = blk * 4 + (tid >> 6), lane = tid & 63;
        int b = wid >> 7, l = wid & 127;
        const float* tr = tok + (b * L + l) * H;
        float p0 = 0, p1 = 0, p2 = 0, p3 = 0, p4 = 0, p5 = 0, p6 = 0, p7 = 0;
        #pragma unroll
        for (int j = 0; j < H / 64; ++j) {
            int h = lane + j * 64;
            float t = tr[h];
            p0 += t * fcw[h];
            p1 += t * fcw[H + h];
            p4 += t * fcw[4 * H + h];
            p5 += t * fcw[5 * H + h];
            p2 += t * fcw[2 * H + h];
            p3 += t * fcw[3 * H + h];
            p6 += t * fcw[6 * H + h];
            p7 += t * fcw[7 * H + h];
        }
        p0 = wave_sum(p0); p1 = wave_sum(p1); p4 = wave_sum(p4); p5 = wave_sum(p5);
        p2 = wave_sum(p2); p3 = wave_sum(p3); p6 = wave_sum(p6); p7 = wave_sum(p7);
        if (lane == 0) {
            int idx = b * L + l;
            out[OUT_FHS + idx] = p0 + fcb[0];
            out[OUT_FHE + idx] = p1 + fcb[1];
            out[OUT_BTS + idx] = p4 + fcb[4];
            out[OUT_BTE + idx] = p5 + fcb[5];
            float* t2 = ws + WS_T2;
            t2[idx] = p2; t2[BL + idx] = p3; t2[2 * BL + idx] = p6; t2[3 * BL + idx] = p7;
        }
    } else if (blk < 176) {
        // b_rel_embs row -> bf16
        int r = blk - 128;
        if (tid < D) lds[tid] = b_rt[r * D + tid];
        __syncthreads();
        #pragma unroll
        for (int jj = 0; jj < 3; ++jj) {
            int h = tid + jj * 256;
            float acc = rpb[h];
            for (int k = 0; k < D; ++k) acc += lds[k] * rpw[k * H + h];
            ub[UB_BREL + r * H + h] = f2bf(acc);
        }
    } else if (blk < 200) {
        // tok -> bf16
        int base = (blk - 176) * 16384;
        #pragma unroll
        for (int i = 0; i < 16; ++i) {
            int e = base + i * 1024 + tid * 4;
            float4 v = *(const float4*)&tok[e];
            *(ushort4*)&ub[UB_TOK + e] = f2bf4(v);
        }
    } else if (blk < 204) {
        // f_rel -> bf16
        int base = (blk - 200) * 9216;
        #pragma unroll
        for (int i = 0; i < 9; ++i) {
            int e = base + i * 1024 + tid * 4;
            float4 v = *(const float4*)&f_rel[e];
            *(ushort4*)&ub[UB_FREL + e] = f2bf4(v);
        }
    } else if (blk == 204) {
        // h_gs -> bf16
        #pragma unroll
        for (int i = 0; i < 3; ++i) {
            int e = i * 1024 + tid * 4;
            float4 v = *(const float4*)&h_gs[e];
            *(ushort4*)&ub[UB_HGS + e] = f2bf4(v);
        }
    } else {
        // big_w[j] (k,n) -> WT[j] (n,k) bf16, 64x64 tiles
        int wb = blk - 205;
        int j = wb / 144, t = wb - j * 144;
        int kt = t / 12, nt = t - kt * 12;
        int k0 = kt * 64, n0 = nt * 64;
        const float* W = bigw + (size_t)j * H * H;
        ushort* WT = ub + UB_WT + (size_t)j * H * H;
        #pragma unroll
        for (int it = 0; it < 4; ++it) {
            int kk = (tid >> 4) + it * 16;
            int nn = (tid & 15) * 4;
            float4 v = *(const float4*)&W[(k0 + kk) * H + n0 + nn];
            lds[kk * 65 + nn + 0] = v.x;
            lds[kk * 65 + nn + 1] = v.y;
            lds[kk * 65 + nn + 2] = v.z;
            lds[kk * 65 + nn + 3] = v.w;
        }
        __syncthreads();
        #pragma unroll
        for (int it = 0; it < 4; ++it) {
            int nn = (tid >> 4) + it * 16;
            int kk = (tid & 15) * 4;
            float4 v;
            v.x = lds[(kk + 0) * 65 + nn];
            v.y = lds[(kk + 1) * 65 + nn];
            v.z = lds[(kk + 2) * 65 + nn];
            v.w = lds[(kk + 3) * 65 + nn];
            *(ushort4*)&WT[(n0 + nn) * H + k0 + kk] = f2bf4(v);
        }
    }
}

// ---- all 10 GEMMs, 64x64 tile, BK=64, LDS-staged bf16, 4 waves of 32x32.
// Last block = span extraction (ballot; sigmoid(x)>0.5 <=> x>0).
struct MfmaDesc { const ushort* A; const ushort* W; const float* bias; float* O; int M; };
struct MfmaArgs { MfmaDesc d[10]; int off[11]; };

constexpr int AST = 72;   // LDS row stride in shorts

__global__ __launch_bounds__(256) void k_mfma(MfmaArgs args, const float* __restrict__ out,
                                              float* __restrict__ ws) {
    int blk = blockIdx.x, tid = threadIdx.x;
    int lane = tid & 63, w = tid >> 6;

    if (blk == 624) {   // span tail block
        for (int pp = w; pp < 8; pp += 4) {
            int ctx = pp >> 2, b = pp & 3;
            const float* sp = out + (ctx ? OUT_BTS : OUT_FHS) + b * L;
            const float* ep = out + (ctx ? OUT_BTE : OUT_FHE) + b * L;
            unsigned long long s0 = __ballot(sp[lane] > 0.f);
            unsigned long long s1 = __ballot(sp[lane + 64] > 0.f);
            unsigned long long e0 = __ballot(ep[lane] > 0.f);
            unsigned long long e1 = __ballot(ep[lane + 64] > 0.f);
            if (lane == 0) {
                int s, len;
                if (s0 == 0 && s1 == 0) { s = 0; len = 0; }
                else {
                    s = s0 ? __builtin_ctzll(s0) : 64 + __builtin_ctzll(s1);
                    int e;
                    if (s < 64) {
                        unsigned long long m0 = (e0 >> s) << s;
                        e = m0 ? __builtin_ctzll(m0) : (e1 ? 64 + __builtin_ctzll(e1) : s);
                    } else {
                        int s2 = s - 64;
                        unsigned long long m1 = (e1 >> s2) << s2;
                        e = m1 ? 64 + __builtin_ctzll(m1) : s;
                    }
                    len = e - s + 1;
                }
                int* span = (int*)(ws + WS_SPAN);
                span[ctx * 8 + b] = s;
                span[ctx * 8 + 4 + b] = len;
            }
        }
        return;
    }

    int p = 0;
    while (p < 9 && blk >= args.off[p + 1]) ++p;
    MfmaDesc dd = args.d[p];
    int t = blk - args.off[p];
    int mt = t / 12, nt = t - mt * 12;
    int m0 = mt * 64, n0 = nt * 64;

    __shared__ __align__(16) ushort As[64 * AST];
    __shared__ __align__(16) ushort Bs[64 * AST];

    int seg = tid & 7;
    int row2 = tid >> 3;
    int Mm1 = dd.M - 1;

    int wm = w >> 1, wn = w & 1;
    int lr = lane & 15, q = lane >> 4;
    floatx4 acc[2][2] = {};

    for (int k0 = 0; k0 < H; k0 += 64) {
        #pragma unroll
        for (int it = 0; it < 2; ++it) {
            int r = row2 + it * 32;
            int ar = min(m0 + r, Mm1);
            *(short8*)&As[r * AST + seg * 8] = *(const short8*)&dd.A[ar * H + k0 + seg * 8];
            *(short8*)&Bs[r * AST + seg * 8] = *(const short8*)&dd.W[(n0 + r) * H + k0 + seg * 8];
        }
        __syncthreads();
        #pragma unroll
        for (int ks = 0; ks < 64; ks += 32) {
            short8 a0 = *(const short8*)&As[(wm * 32 + lr) * AST + ks + q * 8];
            short8 a1 = *(const short8*)&As[(wm * 32 + 16 + lr) * AST + ks + q * 8];
            short8 b0 = *(const short8*)&Bs[(wn * 32 + lr) * AST + ks + q * 8];
            short8 b1 = *(const short8*)&Bs[(wn * 32 + 16 + lr) * AST + ks + q * 8];
            acc[0][0] = __builtin_amdgcn_mfma_f32_16x16x32_bf16(a0, b0, acc[0][0], 0, 0, 0);
            acc[0][1] = __builtin_amdgcn_mfma_f32_16x16x32_bf16(a0, b1, acc[0][1], 0, 0, 0);
            acc[1][0] = __builtin_amdgcn_mfma_f32_16x16x32_bf16(a1, b0, acc[1][0], 0, 0, 0);
            acc[1][1] = __builtin_amdgcn_mfma_f32_16x16x32_bf16(a1, b1, acc[1][1], 0, 0, 0);
        }
        __syncthreads();
    }

    #pragma unroll
    for (int j = 0; j < 2; ++j) {
        int col = n0 + wn * 32 + j * 16 + lr;
        float bv = dd.bias[col];
        #pragma unroll
        for (int i = 0; i < 2; ++i) {
            int rowb = m0 + wm * 32 + i * 16 + q * 4;
            #pragma unroll
            for (int rr = 0; rr < 4; ++rr) {
                int row = rowb + rr;
                if (row < dd.M) dd.O[row * H + col] = acc[i][j][rr] + bv;
            }
        }
    }
}

// ---- attention scores via exp-product tanh: v[b,r,l] = sum_h tanh(x+pr)*vw + vb
// tanh(x+p) = 1 - 2/(1 + e^{2x}*e^{2p}): e^{2x} hoisted per-l, e^{2p} per-r.
// 512 blocks (2 l's each) for 2 blocks/CU.
__global__ __launch_bounds__(256) void k_attn_v(float* __restrict__ ws,
                                                const float* __restrict__ fcw,
                                                const float* __restrict__ fcb) {
    int ctx = blockIdx.y;
    int b = blockIdx.x >> 6;
    int l0 = (blockIdx.x & 63) * 2;
    int lane = threadIdx.x & 63, w = threadIdx.x >> 6;
    constexpr float TWO_LOG2E = 2.8853900817779268f;

    const float* pxb = ws + (ctx ? 3 : 2) * P_SZ + (b * L + l0) * H;
    const float* pg = ws + (ctx ? WS_PGB : WS_PGF) + b * H;
    const float* pr = ws + (ctx ? WS_PRB : WS_PRF);
    float* vout = ws + (ctx ? WS_VB : WS_VF) + b * R * L + l0;

    float ex[2][12], vw[12];
    float svw = 0.f;
    #pragma unroll
    for (int j = 0; j < 12; ++j) {
        int h = lane + j * 64;
        float g = pg[h];
        vw[j] = fcw[8 * H + h];
        svw += vw[j];
        #pragma unroll
        for (int ll = 0; ll < 2; ++ll)
            ex[ll][j] = __builtin_amdgcn_exp2f((pxb[ll * H + h] + g) * TWO_LOG2E);
    }
    float vb = fcb[8];

    for (int r = w; r < R; r += 4) {
        const float* prr = pr + r * H;
        float ep[12];
        #pragma unroll
        for (int j = 0; j < 12; ++j)
            ep[j] = __builtin_amdgcn_exp2f(prr[lane + j * 64] * TWO_LOG2E);
        float n0 = 0.f, n1 = 0.f;   // sum vw * rcp(1+u)
        #pragma unroll
        for (int j = 0; j < 12; ++j) {
            n0 += vw[j] * __builtin_amdgcn_rcpf(1.0f + ex[0][j] * ep[j]);
            n1 += vw[j] * __builtin_amdgcn_rcpf(1.0f + ex[1][j] * ep[j]);
        }
        float p0 = svw - 2.f * n0;
        float p1 = svw - 2.f * n1;
        p0 = wave_sum(p0);
        p1 = wave_sum(p1);
        if (lane == 0) {
            vout[r * L + 0] = p0 + vb;
            vout[r * L + 1] = p1 + vb;
        }
    }
}

// ---- fused epilogue: softmax+c (recomputed per block), u-dots, broadcast write
// 128 blocks (8 l's each)
__global__ __launch_bounds__(256) void k_epi(const float* __restrict__ tok,
                                             const float* __restrict__ fcw,
                                             const float* __restrict__ fcb,
                                             float* __restrict__ ws,
                                             float* __restrict__ out) {
    int ctx = blockIdx.z, b = blockIdx.y, l0 = blockIdx.x * 8;
    int lane = threadIdx.x & 63, w = threadIdx.x >> 6;
    __shared__ float c2[2][R];
    __shared__ float uu[2][8];

    // phase A: softmax over L + c[b,r] for both heads of this ctx
    const float* vbase = ws + (ctx ? WS_VB : WS_VF) + b * R * L;
    const float* tA = ws + WS_T2 + (ctx * 2 + 0) * BL + b * L;
    const float* tB = ws + WS_T2 + (ctx * 2 + 1) * BL + b * L;
    for (int r = w; r < R; r += 4) {
        const float* vr = vbase + r * L;
        float x0 = vr[lane], x1 = vr[lane + 64];
        float m = fmaxf(x0, x1);
        #pragma unroll
        for (int off = 32; off; off >>= 1) m = fmaxf(m, __shfl_xor(m, off));
        constexpr float LOG2E = 1.4426950408889634f;
        float e0 = __builtin_amdgcn_exp2f((x0 - m) * LOG2E);
        float e1 = __builtin_amdgcn_exp2f((x1 - m) * LOG2E);
        float s = e0 + e1;
        float pa = e0 * tA[lane] + e1 * tA[lane + 64];
        float pb = e0 * tB[lane] + e1 * tB[lane + 64];
        #pragma unroll
        for (int off = 32; off; off >>= 1) {
            s += __shfl_xor(s, off);
            pa += __shfl_xor(pa, off);
            pb += __shfl_xor(pb, off);
        }
        if (lane == 0) {
            float inv = __builtin_amdgcn_rcpf(s);
            c2[0][r] = pa * inv;
            c2[1][r] = pb * inv;
        }
    }

    // phase B: u[l] for 8 l's (2 per wave)
    const int* span = (const int*)(ws + WS_SPAN);
    int s0 = span[ctx * 8 + b], sl = span[ctx * 8 + 4 + b];
    const float* wA = fcw + (ctx ? 6 : 2) * H;
    const float* wB = fcw + (ctx ? 7 : 3) * H;
    const float* pX = ws + (ctx ? 5 : 4) * (size_t)P_SZ;
    const float* pG = ws + (ctx ? 1 : 0) * (size_t)P_SZ;
    #pragma unroll
    for (int i = 0; i < 2; ++i) {
        int l_loc = w * 2 + i, l = l0 + l_loc;
        bool msk = l < sl;
        float mf = msk ? 1.f : 0.f;
        const float* tr = tok + (b * L + l) * H;
        const float* xr = pX + (b * L + l) * H;
        const float* gr = pG + (b * L + (msk ? s0 + l : 0)) * H;
        float pf = 0.f, pg2 = 0.f;
        #pragma unroll
        for (int j = 0; j < 12; ++j) {
            int h = lane + j * 64;
            float sv = tr[h] + xr[h] + mf * gr[h];
            pf += sv * wA[h];
            pg2 += sv * wB[h];
        }
        pf = wave_sum(pf); pg2 = wave_sum(pg2);
        if (lane == 0) { uu[0][l_loc] = pf; uu[1][l_loc] = pg2; }
    }
    __syncthreads();

    // phase C: out[b,l,r] = u[l] + c[r] + bias
    const int out_off4[4] = {OUT_FTS, OUT_FTE, OUT_BHS, OUT_BHE};
    float bias0 = fcb[ctx ? 6 : 2], bias1 = fcb[ctx ? 7 : 3];
    int o0 = out_off4[ctx * 2 + 0], o1 = out_off4[ctx * 2 + 1];
    for (int idx = threadIdx.x; idx < 8 * R; idx += 256) {
        int l_loc = idx / R, r = idx - l_loc * R;
        int o = b * (L * R) + (l0 + l_loc) * R + r;
        out[o0 + o] = uu[0][l_loc] + c2[0][r] + bias0;
        out[o1 + o] = uu[1][l_loc] + c2[1][r] + bias1;
    }
}

extern "C" void kernel_launch(void* const* d_in, const int* in_sizes, int n_in,
                              void* d_out, int out_size, void* d_ws, size_t ws_size,
                              hipStream_t stream) {
    const float* h_gs  = (const float*)d_in[0];
    const float* tok   = (const float*)d_in[1];
    const float* f_rel = (const float*)d_in[2];
    const float* b_rt  = (const float*)d_in[3];
    const float* rpw   = (const float*)d_in[4];
    const float* rpb   = (const float*)d_in[5];
    const float* fcw   = (const float*)d_in[6];
    const float* fcb   = (const float*)d_in[7];
    const float* bigw  = (const float*)d_in[8];
    const float* bigb  = (const float*)d_in[9];
    float* out = (float*)d_out;
    float* ws  = (float*)d_ws;
    const ushort* ub = (const ushort*)(ws + WS_BF16);

    k_setup<<<1645, 256, 0, stream>>>(tok, h_gs, f_rel, b_rt, rpw, rpb, fcw, fcb, bigw, out, ws);

    MfmaArgs ma;
    const int wj[6] = {0, 1, 4, 7, 8, 9};
    for (int j = 0; j < 6; ++j)
        ma.d[j] = MfmaDesc{ub + UB_TOK, ub + UB_WT + (size_t)wj[j] * H * H,
                           bigb + wj[j] * H, ws + (size_t)j * P_SZ, BL};
    ma.d[6] = MfmaDesc{ub + UB_FREL, ub + UB_WT + 2 * (size_t)H * H, bigb + 2 * H, ws + WS_PRF, R};
    ma.d[7] = MfmaDesc{ub + UB_BREL, ub + UB_WT + 5 * (size_t)H * H, bigb + 5 * H, ws + WS_PRB, R};
    ma.d[8] = MfmaDesc{ub + UB_HGS,  ub + UB_WT + 3 * (size_t)H * H, bigb + 3 * H, ws + WS_PGF, B};
    ma.d[9] = MfmaDesc{ub + UB_HGS,  ub + UB_WT + 6 * (size_t)H * H, bigb + 6 * H, ws + WS_PGB, B};
    int off = 0;
    for (int p = 0; p < 10; ++p) {
        ma.off[p] = off;
        int mtiles = (ma.d[p].M + 63) / 64;
        off += mtiles * 12;
    }
    ma.off[10] = off;   // 624
    k_mfma<<<off + 1, 256, 0, stream>>>(ma, out, ws);

    k_attn_v<<<dim3(256, 2), 256, 0, stream>>>(ws, fcw, fcb);
    k_epi<<<dim3(16, 4, 2), 256, 0, stream>>>(tok, fcw, fcb, ws, out);
}